// Round 9
// baseline (177.539 us; speedup 1.0000x reference)
//
#include <hip/hip_runtime.h>

#define T_TOK 16384
#define HDIM  4096
#define NEXP  64
#define TAU   2e-4f
#define BM    128

typedef unsigned short u16;
typedef u16   u16x8  __attribute__((ext_vector_type(8)));
typedef __bf16 bf16x8 __attribute__((ext_vector_type(8)));
typedef float f32x4  __attribute__((ext_vector_type(4)));

__global__ void zero_counter(int* counter) {
    if (threadIdx.x == 0) counter[0] = 0;
}

// ---------------------------------------------------------------------------
// Pre-pass: (a) W -> bf16 hi/lo in per-k-chunk MFMA fragment order, stored
// UNSWIZZLED (W is now read directly from global by the GEMM; the XOR was
// only ever for LDS banks); (b) fp32 transpose wt4[k4][e] for f64 repair.
// Chunk c = 1024 x 16B units [hi 512 | lo 512]; unit U = ks*256 + nt*64 +
// 16*g + (e&15), where k8 = 4*ks+g is the k-octet. Lane l of a wave reading
// unit base+l gets fragment {col=l&15, k-pack g=l>>4} — the layout verified
// on HW in rounds 4-8 (A and B share the same (lane,j)->k packing).
// ---------------------------------------------------------------------------
__global__ __launch_bounds__(256)
void wsplit_kernel(const float* __restrict__ w, u16x8* __restrict__ wfrag,
                   float4* __restrict__ wt4) {
    const int id  = blockIdx.x * 256 + threadIdx.x;   // 0..32767
    const int e   = id >> 9;
    const int k8g = id & 511;
    const int k   = k8g * 8;

    const float* wp = w + (size_t)e * HDIM + k;
    const float4 v0 = *(const float4*)wp;
    const float4 v1 = *(const float4*)(wp + 4);

    wt4[(size_t)(2 * k8g) * NEXP + e]     = v0;
    wt4[(size_t)(2 * k8g + 1) * NEXP + e] = v1;

    const float fv[8] = {v0.x, v0.y, v0.z, v0.w, v1.x, v1.y, v1.z, v1.w};
    bf16x8 hv, lv;
#pragma unroll
    for (int j = 0; j < 8; ++j) {
        const __bf16 h = (__bf16)fv[j];
        hv[j] = h;
        lv[j] = (__bf16)(fv[j] - (float)h);
    }
    const int chunk = k >> 6;
    const int k8 = (k >> 3) & 7, ks = k8 >> 2, g = k8 & 3, nt = e >> 4;
    const int U = ks * 256 + nt * 64 + 16 * g + (e & 15);
    wfrag[(size_t)chunk * 1024 + U]       = __builtin_bit_cast(u16x8, hv);
    wfrag[(size_t)chunk * 1024 + 512 + U] = __builtin_bit_cast(u16x8, lv);
}

// ---------------------------------------------------------------------------
// MFMA GEMM v3. Tile 128x64, BK=64, 4 waves, round-6 two-barrier structure.
//  - W fragments read DIRECTLY from global (contiguous 1KB/wave/instr,
//    L2-resident 1 MiB) — no W in LDS, no 4x redundant W LDS reads.
//  - LDS holds only X hi/lo (32 KiB), verified ^k8 swizzle.
//  - X split uses native __bf16 casts (v_cvt_pk_bf16_f32 packing).
// ---------------------------------------------------------------------------
__global__ __launch_bounds__(256, 4)
void gate_gemm_mfma(const float* __restrict__ x, const u16x8* __restrict__ wfrag,
                    float* __restrict__ partial, int ksplit) {
    const int b      = blockIdx.x;
    const int kslice = b % ksplit;
    const int tblk   = b / ksplit;
    const int kspan  = HDIM / ksplit;
    const int k0     = kslice * kspan;
    const int t0     = tblk * BM;

    __shared__ __align__(16) u16 smem[2048 * 8];   // 32 KiB: X hi 1024 | lo 1024
    u16x8* smemv = (u16x8*)smem;

    const int tid  = threadIdx.x;
    const int lane = tid & 63;
    const int wv   = tid >> 6;

    f32x4 acc[2][4];
#pragma unroll
    for (int m = 0; m < 2; ++m)
#pragma unroll
        for (int nt = 0; nt < 4; ++nt) acc[m][nt] = (f32x4){0.f, 0.f, 0.f, 0.f};

    for (int kc = k0; kc < k0 + kspan; kc += 64) {
        __syncthreads();

        // ---- stage X: 128 rows x 8 k-octets; native-cast bf16 hi/lo split
#pragma unroll
        for (int i = 0; i < 4; ++i) {
            const int L   = tid + 256 * i;   // 0..1023
            const int row = L >> 3;          // 0..127
            const int k8  = L & 7;
            const float* xp = x + (size_t)(t0 + row) * HDIM + kc + 8 * k8;
            const float4 v0 = *(const float4*)xp;
            const float4 v1 = *(const float4*)(xp + 4);
            const float fv[8] = {v0.x, v0.y, v0.z, v0.w, v1.x, v1.y, v1.z, v1.w};
            bf16x8 hv, lv;
#pragma unroll
            for (int j = 0; j < 8; ++j) {
                const __bf16 h = (__bf16)fv[j];
                hv[j] = h;
                lv[j] = (__bf16)(fv[j] - (float)h);
            }
            const int g = k8 & 3, ks = k8 >> 2, mt = row >> 4;
            const int U = ks * 512 + mt * 64 + 16 * g + (row & 15);
            const int phys = U ^ k8;
            smemv[phys]        = __builtin_bit_cast(u16x8, hv);
            smemv[1024 + phys] = __builtin_bit_cast(u16x8, lv);
        }
        __syncthreads();

        // ---- MFMA: A from LDS, B from global (L2). 2 ks x 4 nt x 3 products.
        const u16x8* wsrc = wfrag + (size_t)(kc >> 6) * 1024;
#pragma unroll
        for (int ks2 = 0; ks2 < 2; ++ks2) {
            const int xo = (ks2 << 2) + (lane >> 4);   // this lane's k-octet
            bf16x8 axh[2], axl[2];
#pragma unroll
            for (int m = 0; m < 2; ++m) {
                const int ux = (ks2 * 512 + (wv * 2 + m) * 64 + lane) ^ xo;
                axh[m] = __builtin_bit_cast(bf16x8, smemv[ux]);
                axl[m] = __builtin_bit_cast(bf16x8, smemv[1024 + ux]);
            }
#pragma unroll
            for (int nt = 0; nt < 4; ++nt) {
                const int uwi = ks2 * 256 + nt * 64 + lane;
                const bf16x8 bh = __builtin_bit_cast(bf16x8, wsrc[uwi]);
                const bf16x8 bl = __builtin_bit_cast(bf16x8, wsrc[512 + uwi]);
#pragma unroll
                for (int m = 0; m < 2; ++m) {
                    acc[m][nt] = __builtin_amdgcn_mfma_f32_16x16x32_bf16(axh[m], bh, acc[m][nt], 0, 0, 0);
                    acc[m][nt] = __builtin_amdgcn_mfma_f32_16x16x32_bf16(axh[m], bl, acc[m][nt], 0, 0, 0);
                    acc[m][nt] = __builtin_amdgcn_mfma_f32_16x16x32_bf16(axl[m], bh, acc[m][nt], 0, 0, 0);
                }
            }
        }
    }

    // epilogue: C row = (lane>>4)*4 + r (token), col = lane&15 (expert in nt)
    float* op = partial + (size_t)kslice * T_TOK * NEXP;
    const int ecol = lane & 15;
#pragma unroll
    for (int m = 0; m < 2; ++m) {
        const int trow = t0 + (wv * 2 + m) * 16 + ((lane >> 4) << 2);
#pragma unroll
        for (int nt = 0; nt < 4; ++nt)
#pragma unroll
            for (int r = 0; r < 4; ++r)
                op[(size_t)(trow + r) * NEXP + nt * 16 + ecol] = acc[m][nt][r];
    }
}

// ---------------------------------------------------------------------------
// Top-k (round-6 verbatim): fp32 top-17/token, flag gap<TAU into atomic list.
// Outputs (float32): ew(T,8) | ei(T,8) | ci(T,8) | ia(T,8).
// ---------------------------------------------------------------------------
__global__ __launch_bounds__(256)
void gate_topk_f32(const float* __restrict__ partial, int ksplit,
                   float* __restrict__ out, int* __restrict__ list,
                   int* __restrict__ counter) {
    const int wave = threadIdx.x >> 6;
    const int lane = threadIdx.x & 63;
    const int t = blockIdx.x * 4 + wave;

    float l = 0.f;
    for (int s = 0; s < ksplit; ++s)
        l += partial[(size_t)s * T_TOK * NEXP + (size_t)t * NEXP + lane];

    float v = l;
    const int idx = lane;
    float myval = -3.4e38f;
    int   myidx = 0;
#pragma unroll
    for (int r = 0; r < 17; ++r) {
        float bv = v;
        int   bi = idx;
#pragma unroll
        for (int s = 1; s < 64; s <<= 1) {
            const float ov = __shfl_xor(bv, s);
            const int   oi = __shfl_xor(bi, s);
            if (ov > bv || (ov == bv && oi < bi)) { bv = ov; bi = oi; }
        }
        if (lane == r) { myval = bv; myidx = bi; }
        if (idx == bi) v = -3.4e38f;
    }

    const float nxt = __shfl(myval, (lane + 1) & 63);
    const bool close = (lane < 16) && (myval - nxt < TAU);
    if (__ballot(close) != 0ull) {
        if (lane == 0) { const int p = atomicAdd(counter, 1); list[p] = t; }
    }

    const float m = __shfl(myval, 0);
    const float p = (lane < 16) ? expf(myval - m) : 0.f;
    float s8 = (lane < 8) ? p : 0.f;
#pragma unroll
    for (int s = 1; s < 64; s <<= 1) s8 += __shfl_xor(s8, s);

    float* ew = out;
    float* ei = out + (size_t)T_TOK * 8;
    float* ci = out + (size_t)2 * T_TOK * 8;
    float* ia = out + (size_t)3 * T_TOK * 8;
    if (lane < 8) {
        ew[(size_t)t * 8 + lane] = p / s8;
        ei[(size_t)t * 8 + lane] = (float)myidx;
        ia[(size_t)t * 8 + lane] = (float)myidx;
    } else if (lane < 16) {
        ci[(size_t)t * 8 + (lane - 8)] = (float)myidx;
    }
}

// ---------------------------------------------------------------------------
// Repair phase 1 (round-8 verbatim): wave per (flagged token, k-slice/256).
// ---------------------------------------------------------------------------
__global__ __launch_bounds__(256)
void repair_partial(const float* __restrict__ x, const float4* __restrict__ wt4,
                    const int* __restrict__ list, const int* __restrict__ counter,
                    double* __restrict__ fpart) {
    const int lane = threadIdx.x & 63;
    const int wid  = (int)((blockIdx.x * blockDim.x + threadIdx.x) >> 6);
    const int nw   = (int)((gridDim.x * blockDim.x) >> 6);
    const int nit  = counter[0] * 16;

    for (int it = wid; it < nit; it += nw) {
        const int li = it >> 4;
        const int ks = it & 15;
        const int t  = __builtin_amdgcn_readfirstlane(list[li]);
        const float4* xr4 = (const float4*)(x + (size_t)t * HDIM) + ks * 64;
        const float4* wb  = wt4 + (size_t)ks * 64 * NEXP;

        double a0 = 0.0, a1 = 0.0, a2 = 0.0, a3 = 0.0;
#pragma unroll 4
        for (int j = 0; j < 64; j += 4) {
            const float4 w0 = wb[(size_t)(j + 0) * NEXP + lane];
            const float4 w1 = wb[(size_t)(j + 1) * NEXP + lane];
            const float4 w2 = wb[(size_t)(j + 2) * NEXP + lane];
            const float4 w3 = wb[(size_t)(j + 3) * NEXP + lane];
            const float4 x0 = xr4[j + 0];
            const float4 x1 = xr4[j + 1];
            const float4 x2 = xr4[j + 2];
            const float4 x3 = xr4[j + 3];
            a0 = fma((double)x0.x, (double)w0.x, a0);
            a0 = fma((double)x0.y, (double)w0.y, a0);
            a0 = fma((double)x0.z, (double)w0.z, a0);
            a0 = fma((double)x0.w, (double)w0.w, a0);
            a1 = fma((double)x1.x, (double)w1.x, a1);
            a1 = fma((double)x1.y, (double)w1.y, a1);
            a1 = fma((double)x1.z, (double)w1.z, a1);
            a1 = fma((double)x1.w, (double)w1.w, a1);
            a2 = fma((double)x2.x, (double)w2.x, a2);
            a2 = fma((double)x2.y, (double)w2.y, a2);
            a2 = fma((double)x2.z, (double)w2.z, a2);
            a2 = fma((double)x2.w, (double)w2.w, a2);
            a3 = fma((double)x3.x, (double)w3.x, a3);
            a3 = fma((double)x3.y, (double)w3.y, a3);
            a3 = fma((double)x3.z, (double)w3.z, a3);
            a3 = fma((double)x3.w, (double)w3.w, a3);
        }
        fpart[(size_t)li * 1024 + ks * 64 + lane] = (a0 + a1) + (a2 + a3);
    }
}

// ---------------------------------------------------------------------------
// Repair phase 2 (round-8 verbatim): fixed-order sum of 16 partials,
// f64 top-16, overwrite outputs. Deterministic regardless of list order.
// ---------------------------------------------------------------------------
__global__ __launch_bounds__(256)
void repair_final(const double* __restrict__ fpart, const int* __restrict__ list,
                  const int* __restrict__ counter, float* __restrict__ out) {
    const int lane = threadIdx.x & 63;
    const int wid  = (int)((blockIdx.x * blockDim.x + threadIdx.x) >> 6);
    const int nw   = (int)((gridDim.x * blockDim.x) >> 6);
    const int n    = counter[0];

    for (int li = wid; li < n; li += nw) {
        const int t = __builtin_amdgcn_readfirstlane(list[li]);

        double v = 0.0;
#pragma unroll
        for (int ks = 0; ks < 16; ++ks)
            v += fpart[(size_t)li * 1024 + ks * 64 + lane];

        const int idx = lane;
        double mylog = -1.0e308;
        int    myidx = 0;
#pragma unroll
        for (int r = 0; r < 16; ++r) {
            double bv = v;
            int    bi = idx;
#pragma unroll
            for (int s = 1; s < 64; s <<= 1) {
                const double ov = __shfl_xor(bv, s);
                const int    oi = __shfl_xor(bi, s);
                if (ov > bv || (ov == bv && oi < bi)) { bv = ov; bi = oi; }
            }
            if (lane == r) { mylog = bv; myidx = bi; }
            if (idx == bi) v = -1.0e308;
        }

        const double m = __shfl(mylog, 0);
        const float p = (lane < 16) ? expf((float)(mylog - m)) : 0.f;
        float s8 = (lane < 8) ? p : 0.f;
#pragma unroll
        for (int s = 1; s < 64; s <<= 1) s8 += __shfl_xor(s8, s);

        float* ew = out;
        float* ei = out + (size_t)T_TOK * 8;
        float* ci = out + (size_t)2 * T_TOK * 8;
        float* ia = out + (size_t)3 * T_TOK * 8;
        if (lane < 8) {
            ew[(size_t)t * 8 + lane] = p / s8;
            ei[(size_t)t * 8 + lane] = (float)myidx;
            ia[(size_t)t * 8 + lane] = (float)myidx;
        } else if (lane < 16) {
            ci[(size_t)t * 8 + (lane - 8)] = (float)myidx;
        }
    }
}

extern "C" void kernel_launch(void* const* d_in, const int* in_sizes, int n_in,
                              void* d_out, int out_size, void* d_ws, size_t ws_size,
                              hipStream_t stream) {
    const float* x = (const float*)d_in[0];
    const float* w = (const float*)d_in[1];
    float* out     = (float*)d_out;

    const size_t slice      = (size_t)T_TOK * NEXP * sizeof(float);     // 4 MiB
    const size_t wfragBytes = (size_t)64 * 1024 * 16;                   // 1 MiB
    const size_t wt4Bytes   = (size_t)NEXP * HDIM * sizeof(float);      // 1 MiB
    const size_t fpartBytes = (size_t)T_TOK * 16 * NEXP * sizeof(double); // 128 MiB
    const size_t extra      = wfragBytes + wt4Bytes + fpartBytes +
                              (size_t)T_TOK * sizeof(int) + 64;

    int ksplit = 1;
    if      (ws_size >= 4 * slice + extra) ksplit = 4;
    else if (ws_size >= 2 * slice + extra) ksplit = 2;

    float*  partial = (float*)d_ws;
    u16x8*  wfrag   = (u16x8*)((char*)d_ws + (size_t)ksplit * slice);
    float4* wt4     = (float4*)((char*)wfrag + wfragBytes);
    double* fpart   = (double*)((char*)wt4 + wt4Bytes);
    int*    list    = (int*)((char*)fpart + fpartBytes);
    int*    counter = list + T_TOK;

    zero_counter<<<1, 64, 0, stream>>>(counter);
    wsplit_kernel<<<128, 256, 0, stream>>>(w, wfrag, wt4);
    gate_gemm_mfma<<<ksplit * (T_TOK / BM), 256, 0, stream>>>(x, wfrag, partial, ksplit);
    gate_topk_f32<<<T_TOK / 4, 256, 0, stream>>>(partial, ksplit, out, list, counter);
    repair_partial<<<4096, 256, 0, stream>>>(x, wt4, list, counter, fpart);
    repair_final<<<1024, 256, 0, stream>>>(fpart, list, counter, out);
}

// Round 10
// 159.494 us; speedup vs baseline: 1.1131x; 1.1131x over previous
//
#include <hip/hip_runtime.h>

#define T_TOK 16384
#define HDIM  4096
#define NEXP  64
#define TAU   2e-4f
#define BM    128

typedef unsigned short u16;
typedef u16   u16x8  __attribute__((ext_vector_type(8)));
typedef __bf16 bf16x8 __attribute__((ext_vector_type(8)));
typedef float f32x4  __attribute__((ext_vector_type(4)));

// async global->LDS DMA, 16B per lane (dest = wave-uniform base + lane*16)
__device__ __forceinline__ void gld16(const void* g, void* l) {
    __builtin_amdgcn_global_load_lds(
        (const __attribute__((address_space(1))) void*)g,
        (__attribute__((address_space(3))) void*)l, 16, 0, 0);
}

__global__ void zero_counter(int* counter) {
    if (threadIdx.x == 0) counter[0] = 0;
}

// ---------------------------------------------------------------------------
// Pre-pass (round-9 verbatim): (a) W -> bf16 hi/lo, per-k-chunk MFMA fragment
// order, UNSWIZZLED (GEMM DMA copies it linearly; B-reads are then per-lane
// contiguous -> conflict-free); (b) fp32 transpose wt4[k4][e] for f64 repair.
// Chunk c = 1024 x 16B units [hi 512 | lo 512]; U = ks*256+nt*64+16*g+(e&15).
// ---------------------------------------------------------------------------
__global__ __launch_bounds__(256)
void wsplit_kernel(const float* __restrict__ w, u16x8* __restrict__ wfrag,
                   float4* __restrict__ wt4) {
    const int id  = blockIdx.x * 256 + threadIdx.x;   // 0..32767
    const int e   = id >> 9;
    const int k8g = id & 511;
    const int k   = k8g * 8;

    const float* wp = w + (size_t)e * HDIM + k;
    const float4 v0 = *(const float4*)wp;
    const float4 v1 = *(const float4*)(wp + 4);

    wt4[(size_t)(2 * k8g) * NEXP + e]     = v0;
    wt4[(size_t)(2 * k8g + 1) * NEXP + e] = v1;

    const float fv[8] = {v0.x, v0.y, v0.z, v0.w, v1.x, v1.y, v1.z, v1.w};
    bf16x8 hv, lv;
#pragma unroll
    for (int j = 0; j < 8; ++j) {
        const __bf16 h = (__bf16)fv[j];
        hv[j] = h;
        lv[j] = (__bf16)(fv[j] - (float)h);
    }
    const int chunk = k >> 6;
    const int k8 = (k >> 3) & 7, ks = k8 >> 2, g = k8 & 3, nt = e >> 4;
    const int U = ks * 256 + nt * 64 + 16 * g + (e & 15);
    wfrag[(size_t)chunk * 1024 + U]       = __builtin_bit_cast(u16x8, hv);
    wfrag[(size_t)chunk * 1024 + 512 + U] = __builtin_bit_cast(u16x8, lv);
}

// ---------------------------------------------------------------------------
// MFMA GEMM v4 — m97-style DMA staging. Tile 128x64, BK=64, 4 waves.
// LDS 48 KiB: W bytes [0,16K) = 1024 units, linear wfrag order;
//             X bytes [16K,48K) = 2048 fp32-float4 units, row*16+(k4^(row&15)).
// Staging = 12 global_load_lds per thread (zero VALU round-trip); the bf16
// hi/lo split happens at A-fragment read (same cvt count: each row is read
// by exactly one wave). Two-barrier structure (compiler drains vmcnt at the
// second barrier). B-reads per-lane contiguous; A-reads XOR-swizzled <=2-way.
// ---------------------------------------------------------------------------
__global__ __launch_bounds__(256, 3)
void gate_gemm_mfma(const float* __restrict__ x, const u16x8* __restrict__ wfrag,
                    float* __restrict__ partial, int ksplit) {
    const int b      = blockIdx.x;
    const int kslice = b % ksplit;
    const int tblk   = b / ksplit;
    const int kspan  = HDIM / ksplit;
    const int k0     = kslice * kspan;
    const int t0     = tblk * BM;

    __shared__ __align__(16) unsigned char smem[48 * 1024];

    const int tid  = threadIdx.x;
    const int lane = tid & 63;
    const int wv   = tid >> 6;

    f32x4 acc[2][4];
#pragma unroll
    for (int m = 0; m < 2; ++m)
#pragma unroll
        for (int nt = 0; nt < 4; ++nt) acc[m][nt] = (f32x4){0.f, 0.f, 0.f, 0.f};

    for (int kc = k0; kc < k0 + kspan; kc += 64) {
        __syncthreads();   // previous MFMA phase done reading LDS

        // ---- W DMA: 1024 x 16B, linear copy of pre-ordered wfrag
        const u16x8* wsrc = wfrag + (size_t)(kc >> 6) * 1024;
#pragma unroll
        for (int i = 0; i < 4; ++i) {
            const int u = tid + 256 * i;
            gld16(wsrc + u, smem + (size_t)u * 16);
        }
        // ---- X DMA: 2048 x 16B fp32; inverse-swizzled global source,
        //      linear LDS dest (stored-at-phys p holds logical k4 = p^(row&15))
#pragma unroll
        for (int j = 0; j < 8; ++j) {
            const int u   = tid + 256 * j;
            const int row = u >> 4;
            const int k4l = (u & 15) ^ (row & 15);
            gld16(x + (size_t)(t0 + row) * HDIM + kc + 4 * k4l,
                  smem + 16384 + (size_t)u * 16);
        }
        __syncthreads();   // implicit vmcnt(0) drain -> DMA data visible

        // ---- MFMA: 2 k-steps x 2 M-subtiles x 4 N-tiles x 3 products
        const u16*   wb = (const u16*)smem;
        const float* xb = (const float*)(smem + 16384);
#pragma unroll
        for (int ks2 = 0; ks2 < 2; ++ks2) {
            const int k8 = (ks2 << 2) + (lane >> 4);   // this lane's k-octet
            bf16x8 axh[2], axl[2];
#pragma unroll
            for (int m = 0; m < 2; ++m) {
                const int row = (wv * 2 + m) * 16 + (lane & 15);
                const int p0  = row * 16 + ((2 * k8) ^ (row & 15));
                const int p1  = row * 16 + ((2 * k8 + 1) ^ (row & 15));
                const float4 va = *(const float4*)(xb + 4 * p0);
                const float4 vb = *(const float4*)(xb + 4 * p1);
                const float fv[8] = {va.x, va.y, va.z, va.w, vb.x, vb.y, vb.z, vb.w};
                bf16x8 hv, lv;
#pragma unroll
                for (int j = 0; j < 8; ++j) {
                    const __bf16 h = (__bf16)fv[j];
                    hv[j] = h;
                    lv[j] = (__bf16)(fv[j] - (float)h);
                }
                axh[m] = hv;
                axl[m] = lv;
            }
#pragma unroll
            for (int nt = 0; nt < 4; ++nt) {
                const int uwi = ks2 * 256 + nt * 64 + lane;
                const bf16x8 bh = __builtin_bit_cast(bf16x8, *(const u16x8*)(wb + (size_t)uwi * 8));
                const bf16x8 bl = __builtin_bit_cast(bf16x8, *(const u16x8*)(wb + (size_t)(512 + uwi) * 8));
#pragma unroll
                for (int m = 0; m < 2; ++m) {
                    acc[m][nt] = __builtin_amdgcn_mfma_f32_16x16x32_bf16(axh[m], bh, acc[m][nt], 0, 0, 0);
                    acc[m][nt] = __builtin_amdgcn_mfma_f32_16x16x32_bf16(axh[m], bl, acc[m][nt], 0, 0, 0);
                    acc[m][nt] = __builtin_amdgcn_mfma_f32_16x16x32_bf16(axl[m], bh, acc[m][nt], 0, 0, 0);
                }
            }
        }
    }

    // epilogue: C row = (lane>>4)*4 + r (token), col = lane&15 (expert in nt)
    float* op = partial + (size_t)kslice * T_TOK * NEXP;
    const int ecol = lane & 15;
#pragma unroll
    for (int m = 0; m < 2; ++m) {
        const int trow = t0 + (wv * 2 + m) * 16 + ((lane >> 4) << 2);
#pragma unroll
        for (int nt = 0; nt < 4; ++nt)
#pragma unroll
            for (int r = 0; r < 4; ++r)
                op[(size_t)(trow + r) * NEXP + nt * 16 + ecol] = acc[m][nt][r];
    }
}

// ---------------------------------------------------------------------------
// Top-k (verbatim): fp32 top-17/token, flag gap<TAU into atomic list.
// Outputs (float32): ew(T,8) | ei(T,8) | ci(T,8) | ia(T,8).
// ---------------------------------------------------------------------------
__global__ __launch_bounds__(256)
void gate_topk_f32(const float* __restrict__ partial, int ksplit,
                   float* __restrict__ out, int* __restrict__ list,
                   int* __restrict__ counter) {
    const int wave = threadIdx.x >> 6;
    const int lane = threadIdx.x & 63;
    const int t = blockIdx.x * 4 + wave;

    float l = 0.f;
    for (int s = 0; s < ksplit; ++s)
        l += partial[(size_t)s * T_TOK * NEXP + (size_t)t * NEXP + lane];

    float v = l;
    const int idx = lane;
    float myval = -3.4e38f;
    int   myidx = 0;
#pragma unroll
    for (int r = 0; r < 17; ++r) {
        float bv = v;
        int   bi = idx;
#pragma unroll
        for (int s = 1; s < 64; s <<= 1) {
            const float ov = __shfl_xor(bv, s);
            const int   oi = __shfl_xor(bi, s);
            if (ov > bv || (ov == bv && oi < bi)) { bv = ov; bi = oi; }
        }
        if (lane == r) { myval = bv; myidx = bi; }
        if (idx == bi) v = -3.4e38f;
    }

    const float nxt = __shfl(myval, (lane + 1) & 63);
    const bool close = (lane < 16) && (myval - nxt < TAU);
    if (__ballot(close) != 0ull) {
        if (lane == 0) { const int p = atomicAdd(counter, 1); list[p] = t; }
    }

    const float m = __shfl(myval, 0);
    const float p = (lane < 16) ? expf(myval - m) : 0.f;
    float s8 = (lane < 8) ? p : 0.f;
#pragma unroll
    for (int s = 1; s < 64; s <<= 1) s8 += __shfl_xor(s8, s);

    float* ew = out;
    float* ei = out + (size_t)T_TOK * 8;
    float* ci = out + (size_t)2 * T_TOK * 8;
    float* ia = out + (size_t)3 * T_TOK * 8;
    if (lane < 8) {
        ew[(size_t)t * 8 + lane] = p / s8;
        ei[(size_t)t * 8 + lane] = (float)myidx;
        ia[(size_t)t * 8 + lane] = (float)myidx;
    } else if (lane < 16) {
        ci[(size_t)t * 8 + (lane - 8)] = (float)myidx;
    }
}

// ---------------------------------------------------------------------------
// Repair phase 1 (verbatim): wave per (flagged token, k-slice/256).
// ---------------------------------------------------------------------------
__global__ __launch_bounds__(256)
void repair_partial(const float* __restrict__ x, const float4* __restrict__ wt4,
                    const int* __restrict__ list, const int* __restrict__ counter,
                    double* __restrict__ fpart) {
    const int lane = threadIdx.x & 63;
    const int wid  = (int)((blockIdx.x * blockDim.x + threadIdx.x) >> 6);
    const int nw   = (int)((gridDim.x * blockDim.x) >> 6);
    const int nit  = counter[0] * 16;

    for (int it = wid; it < nit; it += nw) {
        const int li = it >> 4;
        const int ks = it & 15;
        const int t  = __builtin_amdgcn_readfirstlane(list[li]);
        const float4* xr4 = (const float4*)(x + (size_t)t * HDIM) + ks * 64;
        const float4* wb  = wt4 + (size_t)ks * 64 * NEXP;

        double a0 = 0.0, a1 = 0.0, a2 = 0.0, a3 = 0.0;
#pragma unroll 4
        for (int j = 0; j < 64; j += 4) {
            const float4 w0 = wb[(size_t)(j + 0) * NEXP + lane];
            const float4 w1 = wb[(size_t)(j + 1) * NEXP + lane];
            const float4 w2 = wb[(size_t)(j + 2) * NEXP + lane];
            const float4 w3 = wb[(size_t)(j + 3) * NEXP + lane];
            const float4 x0 = xr4[j + 0];
            const float4 x1 = xr4[j + 1];
            const float4 x2 = xr4[j + 2];
            const float4 x3 = xr4[j + 3];
            a0 = fma((double)x0.x, (double)w0.x, a0);
            a0 = fma((double)x0.y, (double)w0.y, a0);
            a0 = fma((double)x0.z, (double)w0.z, a0);
            a0 = fma((double)x0.w, (double)w0.w, a0);
            a1 = fma((double)x1.x, (double)w1.x, a1);
            a1 = fma((double)x1.y, (double)w1.y, a1);
            a1 = fma((double)x1.z, (double)w1.z, a1);
            a1 = fma((double)x1.w, (double)w1.w, a1);
            a2 = fma((double)x2.x, (double)w2.x, a2);
            a2 = fma((double)x2.y, (double)w2.y, a2);
            a2 = fma((double)x2.z, (double)w2.z, a2);
            a2 = fma((double)x2.w, (double)w2.w, a2);
            a3 = fma((double)x3.x, (double)w3.x, a3);
            a3 = fma((double)x3.y, (double)w3.y, a3);
            a3 = fma((double)x3.z, (double)w3.z, a3);
            a3 = fma((double)x3.w, (double)w3.w, a3);
        }
        fpart[(size_t)li * 1024 + ks * 64 + lane] = (a0 + a1) + (a2 + a3);
    }
}

// ---------------------------------------------------------------------------
// Repair phase 2 (verbatim): fixed-order sum of 16 partials, f64 top-16,
// overwrite outputs. Deterministic regardless of list order.
// ---------------------------------------------------------------------------
__global__ __launch_bounds__(256)
void repair_final(const double* __restrict__ fpart, const int* __restrict__ list,
                  const int* __restrict__ counter, float* __restrict__ out) {
    const int lane = threadIdx.x & 63;
    const int wid  = (int)((blockIdx.x * blockDim.x + threadIdx.x) >> 6);
    const int nw   = (int)((gridDim.x * blockDim.x) >> 6);
    const int n    = counter[0];

    for (int li = wid; li < n; li += nw) {
        const int t = __builtin_amdgcn_readfirstlane(list[li]);

        double v = 0.0;
#pragma unroll
        for (int ks = 0; ks < 16; ++ks)
            v += fpart[(size_t)li * 1024 + ks * 64 + lane];

        const int idx = lane;
        double mylog = -1.0e308;
        int    myidx = 0;
#pragma unroll
        for (int r = 0; r < 16; ++r) {
            double bv = v;
            int    bi = idx;
#pragma unroll
            for (int s = 1; s < 64; s <<= 1) {
                const double ov = __shfl_xor(bv, s);
                const int    oi = __shfl_xor(bi, s);
                if (ov > bv || (ov == bv && oi < bi)) { bv = ov; bi = oi; }
            }
            if (lane == r) { mylog = bv; myidx = bi; }
            if (idx == bi) v = -1.0e308;
        }

        const double m = __shfl(mylog, 0);
        const float p = (lane < 16) ? expf((float)(mylog - m)) : 0.f;
        float s8 = (lane < 8) ? p : 0.f;
#pragma unroll
        for (int s = 1; s < 64; s <<= 1) s8 += __shfl_xor(s8, s);

        float* ew = out;
        float* ei = out + (size_t)T_TOK * 8;
        float* ci = out + (size_t)2 * T_TOK * 8;
        float* ia = out + (size_t)3 * T_TOK * 8;
        if (lane < 8) {
            ew[(size_t)t * 8 + lane] = p / s8;
            ei[(size_t)t * 8 + lane] = (float)myidx;
            ia[(size_t)t * 8 + lane] = (float)myidx;
        } else if (lane < 16) {
            ci[(size_t)t * 8 + (lane - 8)] = (float)myidx;
        }
    }
}

extern "C" void kernel_launch(void* const* d_in, const int* in_sizes, int n_in,
                              void* d_out, int out_size, void* d_ws, size_t ws_size,
                              hipStream_t stream) {
    const float* x = (const float*)d_in[0];
    const float* w = (const float*)d_in[1];
    float* out     = (float*)d_out;

    const size_t slice      = (size_t)T_TOK * NEXP * sizeof(float);       // 4 MiB
    const size_t wfragBytes = (size_t)64 * 1024 * 16;                     // 1 MiB
    const size_t wt4Bytes   = (size_t)NEXP * HDIM * sizeof(float);        // 1 MiB
    const size_t fpartBytes = (size_t)T_TOK * 16 * NEXP * sizeof(double); // 128 MiB
    const size_t extra      = wfragBytes + wt4Bytes + fpartBytes +
                              (size_t)T_TOK * sizeof(int) + 64;

    int ksplit = 1;
    if      (ws_size >= 8 * slice + extra) ksplit = 8;
    else if (ws_size >= 4 * slice + extra) ksplit = 4;
    else if (ws_size >= 2 * slice + extra) ksplit = 2;

    float*  partial = (float*)d_ws;
    u16x8*  wfrag   = (u16x8*)((char*)d_ws + (size_t)ksplit * slice);
    float4* wt4     = (float4*)((char*)wfrag + wfragBytes);
    double* fpart   = (double*)((char*)wt4 + wt4Bytes);
    int*    list    = (int*)((char*)fpart + fpartBytes);
    int*    counter = list + T_TOK;

    zero_counter<<<1, 64, 0, stream>>>(counter);
    wsplit_kernel<<<128, 256, 0, stream>>>(w, wfrag, wt4);
    gate_gemm_mfma<<<ksplit * (T_TOK / BM), 256, 0, stream>>>(x, wfrag, partial, ksplit);
    gate_topk_f32<<<T_TOK / 4, 256, 0, stream>>>(partial, ksplit, out, list, counter);
    repair_partial<<<4096, 256, 0, stream>>>(x, wt4, list, counter, fpart);
    repair_final<<<1024, 256, 0, stream>>>(fpart, list, counter, out);
}

// Round 11
// 159.470 us; speedup vs baseline: 1.1133x; 1.0002x over previous
//
#include <hip/hip_runtime.h>

#define T_TOK 16384
#define HDIM  4096
#define NEXP  64
#define TAU   2e-4f
#define BM    128

typedef unsigned short u16;
typedef u16   u16x8  __attribute__((ext_vector_type(8)));
typedef __bf16 bf16x8 __attribute__((ext_vector_type(8)));
typedef float f32x4  __attribute__((ext_vector_type(4)));

// async global->LDS DMA, 16B per lane (dest = wave-uniform base + lane*16)
__device__ __forceinline__ void gld16(const void* g, void* l) {
    __builtin_amdgcn_global_load_lds(
        (const __attribute__((address_space(1))) void*)g,
        (__attribute__((address_space(3))) void*)l, 16, 0, 0);
}

// ---------------------------------------------------------------------------
// Pre-pass: (a) W -> bf16 hi/lo, per-64k-chunk MFMA fragment order, unswizzled
// (verified rounds 4-10); (b) fp32 transpose wt4[k4][e] for f64 repair;
// (c) zeroes the repair counter (fused; block 0 only).
// Chunk c64 = 1024 x 16B units [hi 512 | lo 512]; U = ks*256+nt*64+16*g+(e&15).
// ---------------------------------------------------------------------------
__global__ __launch_bounds__(256)
void wsplit_kernel(const float* __restrict__ w, u16x8* __restrict__ wfrag,
                   float4* __restrict__ wt4, int* __restrict__ counter) {
    if (blockIdx.x == 0 && threadIdx.x == 0) counter[0] = 0;

    const int id  = blockIdx.x * 256 + threadIdx.x;   // 0..32767
    const int e   = id >> 9;
    const int k8g = id & 511;
    const int k   = k8g * 8;

    const float* wp = w + (size_t)e * HDIM + k;
    const float4 v0 = *(const float4*)wp;
    const float4 v1 = *(const float4*)(wp + 4);

    wt4[(size_t)(2 * k8g) * NEXP + e]     = v0;
    wt4[(size_t)(2 * k8g + 1) * NEXP + e] = v1;

    const float fv[8] = {v0.x, v0.y, v0.z, v0.w, v1.x, v1.y, v1.z, v1.w};
    bf16x8 hv, lv;
#pragma unroll
    for (int j = 0; j < 8; ++j) {
        const __bf16 h = (__bf16)fv[j];
        hv[j] = h;
        lv[j] = (__bf16)(fv[j] - (float)h);
    }
    const int chunk = k >> 6;
    const int k8 = (k >> 3) & 7, ks = k8 >> 2, g = k8 & 3, nt = e >> 4;
    const int U = ks * 256 + nt * 64 + 16 * g + (e & 15);
    wfrag[(size_t)chunk * 1024 + U]       = __builtin_bit_cast(u16x8, hv);
    wfrag[(size_t)chunk * 1024 + 512 + U] = __builtin_bit_cast(u16x8, lv);
}

// ---------------------------------------------------------------------------
// MFMA GEMM v5 — double-buffered DMA pipeline, ONE barrier per chunk.
// Tile 128x64, BK=32, 4 waves, LDS 48 KiB = 2 buffers x 1536 16B-units:
//   buffer p: W [0,512) = [hi 256 | lo 256] (linear wfrag order, ks=c&1),
//             X [512,1536) = row*8 + (k4 ^ (row&7)), fp32.
// Loop: STAGE(c+1 -> p^1) ; compute(c, p) ; __syncthreads().
// The compiler's vmcnt(0) drain at the barrier lands the prefetch AFTER the
// compute it overlapped. Buffer p: written @ c-1, read @ c, rewritten @ c+1
// -> race-free across the single barrier. A-reads: 8 lanes/bank-quad uniform
// (b128 floor, conflict-free); B-reads per-lane contiguous; X DMA source =
// 8 full 128B lines per wave (coalesced).
// ---------------------------------------------------------------------------
__global__ __launch_bounds__(256, 3)
void gate_gemm_mfma(const float* __restrict__ x, const u16x8* __restrict__ wfrag,
                    float* __restrict__ partial, int ksplit) {
    const int b      = blockIdx.x;
    const int kslice = b % ksplit;
    const int tblk   = b / ksplit;
    const int kspan  = HDIM / ksplit;
    const int k0     = kslice * kspan;
    const int t0     = tblk * BM;
    const int nch    = kspan >> 5;        // chunks of 32 k

    __shared__ __align__(16) unsigned char smem[48 * 1024];

    const int tid  = threadIdx.x;
    const int lane = tid & 63;
    const int wv   = tid >> 6;

    f32x4 acc[2][4];
#pragma unroll
    for (int m = 0; m < 2; ++m)
#pragma unroll
        for (int nt = 0; nt < 4; ++nt) acc[m][nt] = (f32x4){0.f, 0.f, 0.f, 0.f};

    auto stage = [&](int c, int p) {
        const int kc  = k0 + (c << 5);
        const u16x8* wsrc = wfrag + (size_t)(kc >> 6) * 1024 + ((c & 1) << 8);
        unsigned char* base = smem + (size_t)p * 1536 * 16;
        gld16(wsrc + tid,       base + (size_t)tid * 16);          // W hi
        gld16(wsrc + 512 + tid, base + (size_t)(256 + tid) * 16);  // W lo
#pragma unroll
        for (int j = 0; j < 4; ++j) {
            const int u   = tid + 256 * j;     // 0..1023
            const int row = u >> 3;
            const int k4l = (u & 7) ^ (row & 7);
            gld16(x + (size_t)(t0 + row) * HDIM + kc + 4 * k4l,
                  base + (size_t)(512 + u) * 16);
        }
    };

    stage(0, 0);
    __syncthreads();   // vmcnt(0) drain -> buffer 0 ready

    for (int c = 0; c < nch; ++c) {
        const int p = c & 1;
        if (c + 1 < nch) stage(c + 1, p ^ 1);   // prefetch flows during compute

        const u16x8* wb = (const u16x8*)(smem + (size_t)p * 1536 * 16);
        const float* xb = (const float*)(smem + ((size_t)p * 1536 + 512) * 16);
        const int k8 = lane >> 4;

        bf16x8 axh[2], axl[2];
#pragma unroll
        for (int m = 0; m < 2; ++m) {
            const int row = (wv * 2 + m) * 16 + (lane & 15);
            const int p0  = row * 8 + ((2 * k8)     ^ (row & 7));
            const int p1  = row * 8 + ((2 * k8 + 1) ^ (row & 7));
            const float4 va = *(const float4*)(xb + 4 * p0);
            const float4 vb = *(const float4*)(xb + 4 * p1);
            const float fv[8] = {va.x, va.y, va.z, va.w, vb.x, vb.y, vb.z, vb.w};
            bf16x8 hv, lv;
#pragma unroll
            for (int j = 0; j < 8; ++j) {
                const __bf16 h = (__bf16)fv[j];
                hv[j] = h;
                lv[j] = (__bf16)(fv[j] - (float)h);
            }
            axh[m] = hv;
            axl[m] = lv;
        }
#pragma unroll
        for (int nt = 0; nt < 4; ++nt) {
            const bf16x8 bh = __builtin_bit_cast(bf16x8, wb[nt * 64 + lane]);
            const bf16x8 bl = __builtin_bit_cast(bf16x8, wb[256 + nt * 64 + lane]);
#pragma unroll
            for (int m = 0; m < 2; ++m) {
                acc[m][nt] = __builtin_amdgcn_mfma_f32_16x16x32_bf16(axh[m], bh, acc[m][nt], 0, 0, 0);
                acc[m][nt] = __builtin_amdgcn_mfma_f32_16x16x32_bf16(axh[m], bl, acc[m][nt], 0, 0, 0);
                acc[m][nt] = __builtin_amdgcn_mfma_f32_16x16x32_bf16(axl[m], bh, acc[m][nt], 0, 0, 0);
            }
        }
        __syncthreads();   // all waves done with p; prefetch (p^1) drained
    }

    // epilogue: C row = (lane>>4)*4 + r (token), col = lane&15 (expert in nt)
    float* op = partial + (size_t)kslice * T_TOK * NEXP;
    const int ecol = lane & 15;
#pragma unroll
    for (int m = 0; m < 2; ++m) {
        const int trow = t0 + (wv * 2 + m) * 16 + ((lane >> 4) << 2);
#pragma unroll
        for (int nt = 0; nt < 4; ++nt)
#pragma unroll
            for (int r = 0; r < 4; ++r)
                op[(size_t)(trow + r) * NEXP + nt * 16 + ecol] = acc[m][nt][r];
    }
}

// ---------------------------------------------------------------------------
// Top-k (verbatim): fp32 top-17/token, flag gap<TAU into atomic list.
// Outputs (float32): ew(T,8) | ei(T,8) | ci(T,8) | ia(T,8).
// ---------------------------------------------------------------------------
__global__ __launch_bounds__(256)
void gate_topk_f32(const float* __restrict__ partial, int ksplit,
                   float* __restrict__ out, int* __restrict__ list,
                   int* __restrict__ counter) {
    const int wave = threadIdx.x >> 6;
    const int lane = threadIdx.x & 63;
    const int t = blockIdx.x * 4 + wave;

    float l = 0.f;
    for (int s = 0; s < ksplit; ++s)
        l += partial[(size_t)s * T_TOK * NEXP + (size_t)t * NEXP + lane];

    float v = l;
    const int idx = lane;
    float myval = -3.4e38f;
    int   myidx = 0;
#pragma unroll
    for (int r = 0; r < 17; ++r) {
        float bv = v;
        int   bi = idx;
#pragma unroll
        for (int s = 1; s < 64; s <<= 1) {
            const float ov = __shfl_xor(bv, s);
            const int   oi = __shfl_xor(bi, s);
            if (ov > bv || (ov == bv && oi < bi)) { bv = ov; bi = oi; }
        }
        if (lane == r) { myval = bv; myidx = bi; }
        if (idx == bi) v = -3.4e38f;
    }

    const float nxt = __shfl(myval, (lane + 1) & 63);
    const bool close = (lane < 16) && (myval - nxt < TAU);
    if (__ballot(close) != 0ull) {
        if (lane == 0) { const int p = atomicAdd(counter, 1); list[p] = t; }
    }

    const float m = __shfl(myval, 0);
    const float p = (lane < 16) ? expf(myval - m) : 0.f;
    float s8 = (lane < 8) ? p : 0.f;
#pragma unroll
    for (int s = 1; s < 64; s <<= 1) s8 += __shfl_xor(s8, s);

    float* ew = out;
    float* ei = out + (size_t)T_TOK * 8;
    float* ci = out + (size_t)2 * T_TOK * 8;
    float* ia = out + (size_t)3 * T_TOK * 8;
    if (lane < 8) {
        ew[(size_t)t * 8 + lane] = p / s8;
        ei[(size_t)t * 8 + lane] = (float)myidx;
        ia[(size_t)t * 8 + lane] = (float)myidx;
    } else if (lane < 16) {
        ci[(size_t)t * 8 + (lane - 8)] = (float)myidx;
    }
}

// ---------------------------------------------------------------------------
// Repair phase 1 (verbatim): wave per (flagged token, k-slice/256).
// ---------------------------------------------------------------------------
__global__ __launch_bounds__(256)
void repair_partial(const float* __restrict__ x, const float4* __restrict__ wt4,
                    const int* __restrict__ list, const int* __restrict__ counter,
                    double* __restrict__ fpart) {
    const int lane = threadIdx.x & 63;
    const int wid  = (int)((blockIdx.x * blockDim.x + threadIdx.x) >> 6);
    const int nw   = (int)((gridDim.x * blockDim.x) >> 6);
    const int nit  = counter[0] * 16;

    for (int it = wid; it < nit; it += nw) {
        const int li = it >> 4;
        const int ks = it & 15;
        const int t  = __builtin_amdgcn_readfirstlane(list[li]);
        const float4* xr4 = (const float4*)(x + (size_t)t * HDIM) + ks * 64;
        const float4* wb  = wt4 + (size_t)ks * 64 * NEXP;

        double a0 = 0.0, a1 = 0.0, a2 = 0.0, a3 = 0.0;
#pragma unroll 4
        for (int j = 0; j < 64; j += 4) {
            const float4 w0 = wb[(size_t)(j + 0) * NEXP + lane];
            const float4 w1 = wb[(size_t)(j + 1) * NEXP + lane];
            const float4 w2 = wb[(size_t)(j + 2) * NEXP + lane];
            const float4 w3 = wb[(size_t)(j + 3) * NEXP + lane];
            const float4 x0 = xr4[j + 0];
            const float4 x1 = xr4[j + 1];
            const float4 x2 = xr4[j + 2];
            const float4 x3 = xr4[j + 3];
            a0 = fma((double)x0.x, (double)w0.x, a0);
            a0 = fma((double)x0.y, (double)w0.y, a0);
            a0 = fma((double)x0.z, (double)w0.z, a0);
            a0 = fma((double)x0.w, (double)w0.w, a0);
            a1 = fma((double)x1.x, (double)w1.x, a1);
            a1 = fma((double)x1.y, (double)w1.y, a1);
            a1 = fma((double)x1.z, (double)w1.z, a1);
            a1 = fma((double)x1.w, (double)w1.w, a1);
            a2 = fma((double)x2.x, (double)w2.x, a2);
            a2 = fma((double)x2.y, (double)w2.y, a2);
            a2 = fma((double)x2.z, (double)w2.z, a2);
            a2 = fma((double)x2.w, (double)w2.w, a2);
            a3 = fma((double)x3.x, (double)w3.x, a3);
            a3 = fma((double)x3.y, (double)w3.y, a3);
            a3 = fma((double)x3.z, (double)w3.z, a3);
            a3 = fma((double)x3.w, (double)w3.w, a3);
        }
        fpart[(size_t)li * 1024 + ks * 64 + lane] = (a0 + a1) + (a2 + a3);
    }
}

// ---------------------------------------------------------------------------
// Repair phase 2 (verbatim): fixed-order sum of 16 partials, f64 top-16,
// overwrite outputs. Deterministic regardless of list order.
// ---------------------------------------------------------------------------
__global__ __launch_bounds__(256)
void repair_final(const double* __restrict__ fpart, const int* __restrict__ list,
                  const int* __restrict__ counter, float* __restrict__ out) {
    const int lane = threadIdx.x & 63;
    const int wid  = (int)((blockIdx.x * blockDim.x + threadIdx.x) >> 6);
    const int nw   = (int)((gridDim.x * blockDim.x) >> 6);
    const int n    = counter[0];

    for (int li = wid; li < n; li += nw) {
        const int t = __builtin_amdgcn_readfirstlane(list[li]);

        double v = 0.0;
#pragma unroll
        for (int ks = 0; ks < 16; ++ks)
            v += fpart[(size_t)li * 1024 + ks * 64 + lane];

        const int idx = lane;
        double mylog = -1.0e308;
        int    myidx = 0;
#pragma unroll
        for (int r = 0; r < 16; ++r) {
            double bv = v;
            int    bi = idx;
#pragma unroll
            for (int s = 1; s < 64; s <<= 1) {
                const double ov = __shfl_xor(bv, s);
                const int    oi = __shfl_xor(bi, s);
                if (ov > bv || (ov == bv && oi < bi)) { bv = ov; bi = oi; }
            }
            if (lane == r) { mylog = bv; myidx = bi; }
            if (idx == bi) v = -1.0e308;
        }

        const double m = __shfl(mylog, 0);
        const float p = (lane < 16) ? expf((float)(mylog - m)) : 0.f;
        float s8 = (lane < 8) ? p : 0.f;
#pragma unroll
        for (int s = 1; s < 64; s <<= 1) s8 += __shfl_xor(s8, s);

        float* ew = out;
        float* ei = out + (size_t)T_TOK * 8;
        float* ci = out + (size_t)2 * T_TOK * 8;
        float* ia = out + (size_t)3 * T_TOK * 8;
        if (lane < 8) {
            ew[(size_t)t * 8 + lane] = p / s8;
            ei[(size_t)t * 8 + lane] = (float)myidx;
            ia[(size_t)t * 8 + lane] = (float)myidx;
        } else if (lane < 16) {
            ci[(size_t)t * 8 + (lane - 8)] = (float)myidx;
        }
    }
}

extern "C" void kernel_launch(void* const* d_in, const int* in_sizes, int n_in,
                              void* d_out, int out_size, void* d_ws, size_t ws_size,
                              hipStream_t stream) {
    const float* x = (const float*)d_in[0];
    const float* w = (const float*)d_in[1];
    float* out     = (float*)d_out;

    const size_t slice      = (size_t)T_TOK * NEXP * sizeof(float);       // 4 MiB
    const size_t wfragBytes = (size_t)64 * 1024 * 16;                     // 1 MiB
    const size_t wt4Bytes   = (size_t)NEXP * HDIM * sizeof(float);        // 1 MiB
    const size_t fpartBytes = (size_t)T_TOK * 16 * NEXP * sizeof(double); // 128 MiB
    const size_t extra      = wfragBytes + wt4Bytes + fpartBytes +
                              (size_t)T_TOK * sizeof(int) + 64;

    int ksplit = 1;
    if      (ws_size >= 8 * slice + extra) ksplit = 8;
    else if (ws_size >= 4 * slice + extra) ksplit = 4;
    else if (ws_size >= 2 * slice + extra) ksplit = 2;

    float*  partial = (float*)d_ws;
    u16x8*  wfrag   = (u16x8*)((char*)d_ws + (size_t)ksplit * slice);
    float4* wt4     = (float4*)((char*)wfrag + wfragBytes);
    double* fpart   = (double*)((char*)wt4 + wt4Bytes);
    int*    list    = (int*)((char*)fpart + fpartBytes);
    int*    counter = list + T_TOK;

    wsplit_kernel<<<128, 256, 0, stream>>>(w, wfrag, wt4, counter);
    gate_gemm_mfma<<<ksplit * (T_TOK / BM), 256, 0, stream>>>(x, wfrag, partial, ksplit);
    gate_topk_f32<<<T_TOK / 4, 256, 0, stream>>>(partial, ksplit, out, list, counter);
    repair_partial<<<4096, 256, 0, stream>>>(x, wt4, list, counter, fpart);
    repair_final<<<1024, 256, 0, stream>>>(fpart, list, counter, out);
}